// Round 1
// baseline (7253.297 us; speedup 1.0000x reference)
//
#include <hip/hip_runtime.h>
#include <cmath>

#define NB   16
#define LL   1024
#define DD   512
#define NCLS 64

// ---------------------------------------------------------------- zero flags
__global__ void k_zero(int* __restrict__ p, int n) {
  int i = blockIdx.x * blockDim.x + threadIdx.x;
  if (i < n) p[i] = 0;
}

// ---------------------------------------------- fused embed-gather + proj GEMM
// C[m][n] = b1[n] + b2[n] + sum_k emb[x[m]][k] * W[n][k]   (M=16384, N=K=512)
__global__ __launch_bounds__(256) void k_gemm_embed(
    const int* __restrict__ x, const float* __restrict__ emb,
    const float* __restrict__ W, const float* __restrict__ b1,
    const float* __restrict__ b2, float* __restrict__ C)
{
  __shared__ __align__(16) float As[32][68];  // [k][m], +4 pad: aligned + conflict-free
  __shared__ __align__(16) float Ws[32][68];  // [k][n]
  const int tid = threadIdx.x;
  const int n0 = (blockIdx.x & 7) * 64;
  const int m0 = (blockIdx.x >> 3) * 64;
  const int tm = tid & 15, tn = tid >> 4;
  float acc[4][4] = {};

  const int f0 = tid * 2, f1 = tid * 2 + 1;
  const int r0 = f0 >> 3, q0 = f0 & 7;
  const int r1 = f1 >> 3, q1 = f1 & 7;
  const long arow0 = (long)x[m0 + r0] * DD;
  const long arow1 = (long)x[m0 + r1] * DD;
  const long wrow0 = (long)(n0 + r0) * DD;
  const long wrow1 = (long)(n0 + r1) * DD;

  for (int k0 = 0; k0 < DD; k0 += 32) {
    float4 va = *(const float4*)(emb + arow0 + k0 + q0 * 4);
    float4 vb = *(const float4*)(emb + arow1 + k0 + q1 * 4);
    float4 wa = *(const float4*)(W + wrow0 + k0 + q0 * 4);
    float4 wb = *(const float4*)(W + wrow1 + k0 + q1 * 4);
    __syncthreads();   // previous tile fully consumed
    As[q0*4+0][r0]=va.x; As[q0*4+1][r0]=va.y; As[q0*4+2][r0]=va.z; As[q0*4+3][r0]=va.w;
    As[q1*4+0][r1]=vb.x; As[q1*4+1][r1]=vb.y; As[q1*4+2][r1]=vb.z; As[q1*4+3][r1]=vb.w;
    Ws[q0*4+0][r0]=wa.x; Ws[q0*4+1][r0]=wa.y; Ws[q0*4+2][r0]=wa.z; Ws[q0*4+3][r0]=wa.w;
    Ws[q1*4+0][r1]=wb.x; Ws[q1*4+1][r1]=wb.y; Ws[q1*4+2][r1]=wb.z; Ws[q1*4+3][r1]=wb.w;
    __syncthreads();
    #pragma unroll
    for (int kk = 0; kk < 32; ++kk) {
      float4 a = *(const float4*)&As[kk][tm * 4];
      float4 w = *(const float4*)&Ws[kk][tn * 4];
      acc[0][0]+=a.x*w.x; acc[0][1]+=a.x*w.y; acc[0][2]+=a.x*w.z; acc[0][3]+=a.x*w.w;
      acc[1][0]+=a.y*w.x; acc[1][1]+=a.y*w.y; acc[1][2]+=a.y*w.z; acc[1][3]+=a.y*w.w;
      acc[2][0]+=a.z*w.x; acc[2][1]+=a.z*w.y; acc[2][2]+=a.z*w.z; acc[2][3]+=a.z*w.w;
      acc[3][0]+=a.w*w.x; acc[3][1]+=a.w*w.y; acc[3][2]+=a.w*w.z; acc[3][3]+=a.w*w.w;
    }
  }
  float bj[4];
  #pragma unroll
  for (int j = 0; j < 4; ++j)
    bj[j] = b1[n0 + tn * 4 + j] + b2[n0 + tn * 4 + j];
  #pragma unroll
  for (int i = 0; i < 4; ++i) {
    const int m = m0 + tm * 4 + i;
    float4 o = { acc[i][0]+bj[0], acc[i][1]+bj[1], acc[i][2]+bj[2], acc[i][3]+bj[3] };
    *(float4*)(C + (long)m * DD + n0 + tn * 4) = o;
  }
}

// ------------------------------------------------- persistent 2-layer RNN scan
// 256 WGs = 16 batches x 8 slices x 2 layers (layer 2 pipelined, lags by 1 step).
// blockIdx: b = g & 15 (=> batch's 16 WGs share an XCD under %8 round-robin),
// k = g>>4: l = k>>3, s = k&7. Weights live in VGPRs (128/thread, 256 for l=1).
__global__ __launch_bounds__(256, 1) void k_scan(
    const float* __restrict__ W_ih, const float* __restrict__ W_hh,
    const float* __restrict__ b_ih, const float* __restrict__ b_hh,
    float* __restrict__ Bbuf,   // in: xproj layer1, becomes O1 (in-place)
    float* __restrict__ Abuf,   // becomes O2
    int* __restrict__ flags1, int* __restrict__ flags2)
{
  const int g = blockIdx.x;
  const int b = g & 15;
  const int k = g >> 4;
  const int l = k >> 3;
  const int s = k & 7;
  const int tid = threadIdx.x;
  const int row = tid & 63;       // output row within slice (wave-lane)
  const int part = tid >> 6;      // k-range quarter (wave id)
  const int col = s * 64 + row;   // global hidden index

  __shared__ float hS[1024];      // [0:512) h-source A; [512:1024) h-source B (l=1)
  __shared__ float yred[256];

  float wh[128];
  {
    const float* p = W_hh + (long)l * DD * DD + (long)col * DD + part * 128;
    #pragma unroll
    for (int j = 0; j < 128; ++j) wh[j] = p[j];
  }
  float wi[128];
  float bias = 0.f;
  if (l == 1) {
    const float* p = W_ih + (long)DD * DD + (long)col * DD + part * 128;
    #pragma unroll
    for (int j = 0; j < 128; ++j) wi[j] = p[j];
    bias = b_ih[DD + col] + b_hh[DD + col];
  }

  float* Bb = Bbuf + (long)b * LL * DD;
  float* Ab = Abuf + (long)b * LL * DD;

  for (int t = 0; t < LL; ++t) {
    if (l == 0) {
      if (t > 0) {
        if (tid == 0)
          while (__hip_atomic_load(&flags1[(t-1)*NB + b], __ATOMIC_ACQUIRE,
                                   __HIP_MEMORY_SCOPE_AGENT) < 8) {}
        __syncthreads();
        #pragma unroll
        for (int i = 0; i < 2; ++i) {
          int idx = tid + i * 256;
          hS[idx] = __hip_atomic_load(&Bb[(long)(t-1)*DD + idx],
                                      __ATOMIC_RELAXED, __HIP_MEMORY_SCOPE_AGENT);
        }
      }
      __syncthreads();
      float y = 0.f;
      if (t > 0) {
        const float* hp = &hS[part * 128];
        #pragma unroll
        for (int j = 0; j < 128; ++j) y += wh[j] * hp[j];   // hp[j] wave-uniform: LDS broadcast
      }
      yred[tid] = y;
      __syncthreads();
      if (tid < 64) {
        float tot = yred[tid] + yred[tid+64] + yred[tid+128] + yred[tid+192];
        float xv = Bb[(long)t*DD + col];                    // own slice of xproj
        float hv = tanhf(xv + tot);
        __hip_atomic_store(&Bb[(long)t*DD + col], hv,
                           __ATOMIC_RELAXED, __HIP_MEMORY_SCOPE_AGENT);
        if (tid == 0)   // RELEASE RMW waits vmcnt(0) -> wave0's 64 stores visible first
          __hip_atomic_fetch_add(&flags1[t*NB + b], 1,
                                 __ATOMIC_RELEASE, __HIP_MEMORY_SCOPE_AGENT);
      }
    } else {
      if (tid == 0) {
        while (__hip_atomic_load(&flags1[t*NB + b], __ATOMIC_ACQUIRE,
                                 __HIP_MEMORY_SCOPE_AGENT) < 8) {}
        if (t > 0)
          while (__hip_atomic_load(&flags2[(t-1)*NB + b], __ATOMIC_ACQUIRE,
                                   __HIP_MEMORY_SCOPE_AGENT) < 8) {}
      }
      __syncthreads();
      #pragma unroll
      for (int i = 0; i < 2; ++i) {
        int idx = tid + i * 256;
        hS[idx] = __hip_atomic_load(&Bb[(long)t*DD + idx],
                                    __ATOMIC_RELAXED, __HIP_MEMORY_SCOPE_AGENT);
      }
      if (t > 0) {
        #pragma unroll
        for (int i = 0; i < 2; ++i) {
          int idx = tid + i * 256;
          hS[512 + idx] = __hip_atomic_load(&Ab[(long)(t-1)*DD + idx],
                                            __ATOMIC_RELAXED, __HIP_MEMORY_SCOPE_AGENT);
        }
      }
      __syncthreads();
      float y = 0.f;
      {
        const float* hp = &hS[part * 128];
        #pragma unroll
        for (int j = 0; j < 128; ++j) y += wi[j] * hp[j];
      }
      if (t > 0) {
        const float* hp = &hS[512 + part * 128];
        #pragma unroll
        for (int j = 0; j < 128; ++j) y += wh[j] * hp[j];
      }
      yred[tid] = y;
      __syncthreads();
      if (tid < 64) {
        float tot = yred[tid] + yred[tid+64] + yred[tid+128] + yred[tid+192];
        float hv = tanhf(tot + bias);
        __hip_atomic_store(&Ab[(long)t*DD + col], hv,
                           __ATOMIC_RELAXED, __HIP_MEMORY_SCOPE_AGENT);
        if (tid == 0)
          __hip_atomic_fetch_add(&flags2[t*NB + b], 1,
                                 __ATOMIC_RELEASE, __HIP_MEMORY_SCOPE_AGENT);
      }
    }
  }
}

// ------------------------------------------- attention row @ eos + decode head
__global__ __launch_bounds__(256) void k_attn(
    const float* __restrict__ O2, const int* __restrict__ eos,
    const float* __restrict__ Wc, const float* __restrict__ bc,
    const float* __restrict__ Wd, const float* __restrict__ bd,
    float* __restrict__ out)
{
  const int b = blockIdx.x;
  const int tid = threadIdx.x;
  const int te = eos[b];
  __shared__ __align__(16) float q[DD];
  __shared__ float ps[LL];
  __shared__ float red[256];
  __shared__ __align__(16) float din[2 * DD];
  __shared__ __align__(16) float dvec[DD];
  const float* Ob = O2 + (long)b * LL * DD;
  const float4* Ob4 = (const float4*)Ob;

  for (int i = tid; i < DD; i += 256) q[i] = Ob[(long)te * DD + i];
  __syncthreads();
  const float4* q4 = (const float4*)q;

  // masked scores (exact reference mask: s<te keeps score, else -1e9)
  for (int ss = tid; ss < LL; ss += 256) {
    float sc = -1.0e9f;
    if (ss < te) {
      float4 acc = {0.f, 0.f, 0.f, 0.f};
      for (int kq = 0; kq < 128; ++kq) {
        float4 o = Ob4[ss * 128 + kq];
        float4 qq = q4[kq];
        acc.x += o.x*qq.x; acc.y += o.y*qq.y; acc.z += o.z*qq.z; acc.w += o.w*qq.w;
      }
      sc = acc.x + acc.y + acc.z + acc.w;
    }
    ps[ss] = sc;
  }
  __syncthreads();
  // softmax (fp32; exp(-1e9 - m) underflows to 0 exactly like jax fp32)
  float m = -3.0e38f;
  for (int ss = tid; ss < LL; ss += 256) m = fmaxf(m, ps[ss]);
  red[tid] = m; __syncthreads();
  for (int off = 128; off > 0; off >>= 1) {
    if (tid < off) red[tid] = fmaxf(red[tid], red[tid + off]);
    __syncthreads();
  }
  m = red[0]; __syncthreads();
  float lsum = 0.f;
  for (int ss = tid; ss < LL; ss += 256) {
    float e = expf(ps[ss] - m);
    ps[ss] = e; lsum += e;
  }
  __syncthreads();
  red[tid] = lsum; __syncthreads();
  for (int off = 128; off > 0; off >>= 1) {
    if (tid < off) red[tid] += red[tid + off];
    __syncthreads();
  }
  const float inv = 1.0f / red[0];
  __syncthreads();
  for (int ss = tid; ss < LL; ss += 256) ps[ss] *= inv;
  __syncthreads();

  // att_z (threads 0..127) and z-copy (threads 128..255)
  if (tid < 128) {
    float4 acc = {0.f, 0.f, 0.f, 0.f};
    for (int ss = 0; ss < LL; ++ss) {
      float p = ps[ss];
      if (p != 0.0f) {             // uniform branch; skips masked-out rows
        float4 o = Ob4[ss * 128 + tid];
        acc.x += p*o.x; acc.y += p*o.y; acc.z += p*o.z; acc.w += p*o.w;
      }
    }
    ((float4*)din)[tid] = acc;
  } else {
    const int c = tid - 128;
    ((float4*)din)[128 + c] = q4[c];
  }
  __syncthreads();

  // dec_in(1024) @ Wc^T + bc -> dvec(512)
  const float4* din4 = (const float4*)din;
  for (int j = tid; j < DD; j += 256) {
    const float4* wrow = (const float4*)(Wc + (long)j * 2 * DD);
    float4 acc = {0.f, 0.f, 0.f, 0.f};
    for (int iq = 0; iq < 256; ++iq) {
      float4 w = wrow[iq]; float4 d = din4[iq];
      acc.x += w.x*d.x; acc.y += w.y*d.y; acc.z += w.z*d.z; acc.w += w.w*d.w;
    }
    dvec[j] = bc[j] + acc.x + acc.y + acc.z + acc.w;
  }
  __syncthreads();

  // logits
  if (tid < NCLS) {
    const float4* wrow = (const float4*)(Wd + (long)tid * DD);
    const float4* dv4 = (const float4*)dvec;
    float4 acc = {0.f, 0.f, 0.f, 0.f};
    for (int iq = 0; iq < 128; ++iq) {
      float4 w = wrow[iq]; float4 d = dv4[iq];
      acc.x += w.x*d.x; acc.y += w.y*d.y; acc.z += w.z*d.z; acc.w += w.w*d.w;
    }
    out[b * NCLS + tid] = bd[tid] + acc.x + acc.y + acc.z + acc.w;
  }
}

extern "C" void kernel_launch(void* const* d_in, const int* in_sizes, int n_in,
                              void* d_out, int out_size, void* d_ws, size_t ws_size,
                              hipStream_t stream)
{
  const int*   x    = (const int*)  d_in[0];
  const int*   eos  = (const int*)  d_in[1];
  const float* emb  = (const float*)d_in[2];
  const float* W_ih = (const float*)d_in[3];
  const float* W_hh = (const float*)d_in[4];
  const float* b_ih = (const float*)d_in[5];
  const float* b_hh = (const float*)d_in[6];
  const float* Wc   = (const float*)d_in[7];
  const float* bc   = (const float*)d_in[8];
  const float* Wd   = (const float*)d_in[9];
  const float* bd   = (const float*)d_in[10];
  float* out = (float*)d_out;

  // workspace layout: O2 | xproj1->O1 | flags1 | flags2   (~64.1 MiB)
  float* Abuf = (float*)d_ws;
  float* Bbuf = Abuf + (size_t)NB * LL * DD;
  int* flags1 = (int*)(Bbuf + (size_t)NB * LL * DD);
  int* flags2 = flags1 + LL * NB;

  k_zero<<<(2 * LL * NB + 255) / 256, 256, 0, stream>>>(flags1, 2 * LL * NB);
  k_gemm_embed<<<2048, 256, 0, stream>>>(x, emb, W_ih, b_ih, b_hh, Bbuf);
  k_scan<<<256, 256, 0, stream>>>(W_ih, W_hh, b_ih, b_hh, Bbuf, Abuf, flags1, flags2);
  k_attn<<<NB, 256, 0, stream>>>(Abuf, eos, Wc, bc, Wd, bd, out);
}

// Round 2
// 3205.857 us; speedup vs baseline: 2.2625x; 2.2625x over previous
//
#include <hip/hip_runtime.h>
#include <cmath>

#define NB   16
#define LL   1024
#define DD   512
#define NCLS 64

// ---------------------------------------------- fused embed-gather + proj GEMM
// C[m][n] = b1[n] + b2[n] + sum_k emb[x[m]][k] * W[n][k]   (M=16384, N=K=512)
__global__ __launch_bounds__(256) void k_gemm_embed(
    const int* __restrict__ x, const float* __restrict__ emb,
    const float* __restrict__ W, const float* __restrict__ b1,
    const float* __restrict__ b2, float* __restrict__ C)
{
  __shared__ __align__(16) float As[32][68];  // [k][m], +4 pad
  __shared__ __align__(16) float Ws[32][68];  // [k][n]
  const int tid = threadIdx.x;
  const int n0 = (blockIdx.x & 7) * 64;
  const int m0 = (blockIdx.x >> 3) * 64;
  const int tm = tid & 15, tn = tid >> 4;
  float acc[4][4] = {};

  const int f0 = tid * 2, f1 = tid * 2 + 1;
  const int r0 = f0 >> 3, q0 = f0 & 7;
  const int r1 = f1 >> 3, q1 = f1 & 7;
  const long arow0 = (long)x[m0 + r0] * DD;
  const long arow1 = (long)x[m0 + r1] * DD;
  const long wrow0 = (long)(n0 + r0) * DD;
  const long wrow1 = (long)(n0 + r1) * DD;

  for (int k0 = 0; k0 < DD; k0 += 32) {
    float4 va = *(const float4*)(emb + arow0 + k0 + q0 * 4);
    float4 vb = *(const float4*)(emb + arow1 + k0 + q1 * 4);
    float4 wa = *(const float4*)(W + wrow0 + k0 + q0 * 4);
    float4 wb = *(const float4*)(W + wrow1 + k0 + q1 * 4);
    __syncthreads();
    As[q0*4+0][r0]=va.x; As[q0*4+1][r0]=va.y; As[q0*4+2][r0]=va.z; As[q0*4+3][r0]=va.w;
    As[q1*4+0][r1]=vb.x; As[q1*4+1][r1]=vb.y; As[q1*4+2][r1]=vb.z; As[q1*4+3][r1]=vb.w;
    Ws[q0*4+0][r0]=wa.x; Ws[q0*4+1][r0]=wa.y; Ws[q0*4+2][r0]=wa.z; Ws[q0*4+3][r0]=wa.w;
    Ws[q1*4+0][r1]=wb.x; Ws[q1*4+1][r1]=wb.y; Ws[q1*4+2][r1]=wb.z; Ws[q1*4+3][r1]=wb.w;
    __syncthreads();
    #pragma unroll
    for (int kk = 0; kk < 32; ++kk) {
      float4 a = *(const float4*)&As[kk][tm * 4];
      float4 w = *(const float4*)&Ws[kk][tn * 4];
      acc[0][0]+=a.x*w.x; acc[0][1]+=a.x*w.y; acc[0][2]+=a.x*w.z; acc[0][3]+=a.x*w.w;
      acc[1][0]+=a.y*w.x; acc[1][1]+=a.y*w.y; acc[1][2]+=a.y*w.z; acc[1][3]+=a.y*w.w;
      acc[2][0]+=a.z*w.x; acc[2][1]+=a.z*w.y; acc[2][2]+=a.z*w.z; acc[2][3]+=a.z*w.w;
      acc[3][0]+=a.w*w.x; acc[3][1]+=a.w*w.y; acc[3][2]+=a.w*w.z; acc[3][3]+=a.w*w.w;
    }
  }
  float bj[4];
  #pragma unroll
  for (int j = 0; j < 4; ++j)
    bj[j] = b1[n0 + tn * 4 + j] + b2[n0 + tn * 4 + j];
  #pragma unroll
  for (int i = 0; i < 4; ++i) {
    const int m = m0 + tm * 4 + i;
    float4 o = { acc[i][0]+bj[0], acc[i][1]+bj[1], acc[i][2]+bj[2], acc[i][3]+bj[3] };
    *(float4*)(C + (long)m * DD + n0 + tn * 4) = o;
  }
}

// ---------------------------------------------------------------- scan helpers
__device__ __forceinline__ float wave_red8(float y) {
  // sum over 8-lane groups (lanes l^1, l^2, l^4) — stays within 32-lane halves
  y += __int_as_float(__builtin_amdgcn_ds_swizzle(__float_as_int(y), 0x041F));
  y += __int_as_float(__builtin_amdgcn_ds_swizzle(__float_as_int(y), 0x081F));
  y += __int_as_float(__builtin_amdgcn_ds_swizzle(__float_as_int(y), 0x101F));
  return y;
}

__device__ __forceinline__ float poll_ld(const float* p) {
  return __hip_atomic_load(p, __ATOMIC_RELAXED, __HIP_MEMORY_SCOPE_AGENT);
}
__device__ __forceinline__ void enc_st(float* p, float v) {
  __hip_atomic_store(p, v + 2.0f, __ATOMIC_RELAXED, __HIP_MEMORY_SCOPE_AGENT);
}

// ------------------------------------------------- persistent 2-layer RNN scan
// 256 WGs = 16 batches x 16 WGs. Each WG owns 32 rows of ALL THREE matrices
// (Whh1, Wih2, Whh2): 192 weight floats/thread -> no spill. xin2 = Wih2.h1 is a
// register chain (producer == consumer). Handshake = data-poll on h+2 encoding:
// one coherence hop per step, no flags, no fences. h1 pipelined 1 ahead of h2.
__global__ __launch_bounds__(256, 1) void k_scan(
    const float* __restrict__ W_ih, const float* __restrict__ W_hh,
    const float* __restrict__ b_ih, const float* __restrict__ b_hh,
    float* __restrict__ Bbuf,   // in: xproj layer1 -> h1+2 (in-place)
    float* __restrict__ Abuf)   // h2+2 (O2, encoded)
{
  const int g = blockIdx.x;
  const int b = g & 15;            // batch  (16 WGs of a batch land on one XCD slot)
  const int j = g >> 4;            // WG index within batch [0,16)
  const int tid = threadIdx.x;
  const int rl  = tid >> 3;        // row_local [0,32)
  const int part = tid & 7;        // k-part [0,8), 64 elems each
  const int row = j * 32 + rl;     // global hidden row
  const bool leader = (part == 0);

  __shared__ __align__(16) float hS1[2][8 * 68];  // staged h1(tau-1), dbl-buffered
  __shared__ __align__(16) float hS2[2][8 * 68];  // staged h2(tau-3)

  float w1[64], w2[64], w3[64];
  {
    const float* p1 = W_hh + (long)row * DD + part * 64;                 // Whh l0
    const float* p2 = W_ih + (long)DD * DD + (long)row * DD + part * 64; // Wih l1
    const float* p3 = W_hh + (long)DD * DD + (long)row * DD + part * 64; // Whh l1
    #pragma unroll
    for (int q = 0; q < 64; ++q) { w1[q] = p1[q]; w2[q] = p2[q]; w3[q] = p3[q]; }
  }
  const float bias2 = b_ih[DD + row] + b_hh[DD + row];
  float xin2 = 0.f;   // holds xin2(tau-2)+bias2 entering step tau

  float* Bb = Bbuf + (long)b * LL * DD;
  float* Ab = Abuf + (long)b * LL * DD;

  const int i0 = tid, i1 = tid + 256;
  const int d0 = (i0 >> 6) * 68 + (i0 & 63);
  const int d1 = (i1 >> 6) * 68 + (i1 & 63);

  for (int tau = 0; tau <= LL + 1; ++tau) {
    const int bufi = tau & 1;
    float xpv = 0.f;
    // ---- stage h1(tau-1) (data-poll: ready iff > 1) ----
    if (tau >= 1 && tau <= LL) {
      const float* src = Bb + (long)(tau - 1) * DD;
      float v0 = poll_ld(src + i0);
      float v1 = poll_ld(src + i1);
      while (fminf(v0, v1) <= 1.0f) { v0 = poll_ld(src + i0); v1 = poll_ld(src + i1); }
      hS1[bufi][d0] = v0 - 2.0f;
      hS1[bufi][d1] = v1 - 2.0f;
    }
    // ---- stage h2(tau-3) (already old -> usually no spin) ----
    if (tau >= 3) {
      const float* src = Ab + (long)(tau - 3) * DD;
      float u0 = poll_ld(src + i0);
      float u1 = poll_ld(src + i1);
      while (fminf(u0, u1) <= 1.0f) { u0 = poll_ld(src + i0); u1 = poll_ld(src + i1); }
      hS2[bufi][d0] = u0 - 2.0f;
      hS2[bufi][d1] = u1 - 2.0f;
    }
    if (leader && tau < LL) xpv = Bb[(long)tau * DD + row];  // prefetch xproj
    __syncthreads();   // single barrier/step (dbl-buffered LDS)

    const float4* h1p = (const float4*)&hS1[bufi][part * 68];
    const float4* h2p = (const float4*)&hS2[bufi][part * 68];

    // ---- M1: h1(tau) = tanh(xproj + Whh1 . h1(tau-1)) — the critical chain ----
    if (tau < LL) {
      float y = 0.f;
      if (tau >= 1) {
        #pragma unroll
        for (int q = 0; q < 16; ++q) {
          float4 h4 = h1p[q];
          y += w1[4*q+0]*h4.x + w1[4*q+1]*h4.y + w1[4*q+2]*h4.z + w1[4*q+3]*h4.w;
        }
      }
      y = wave_red8(y);
      if (leader) enc_st(Bb + (long)tau * DD + row, tanhf(xpv + y));
    }
    // ---- M3: h2(tau-2) = tanh(xin2(tau-2) + Whh2 . h2(tau-3)) ----
    if (tau >= 2) {
      float y = 0.f;
      if (tau >= 3) {
        #pragma unroll
        for (int q = 0; q < 16; ++q) {
          float4 h4 = h2p[q];
          y += w3[4*q+0]*h4.x + w3[4*q+1]*h4.y + w3[4*q+2]*h4.z + w3[4*q+3]*h4.w;
        }
      }
      y = wave_red8(y);
      if (leader) enc_st(Ab + (long)(tau - 2) * DD + row, tanhf(xin2 + y));
    }
    // ---- M2: xin2(tau-1) = Wih2 . h1(tau-1) + bias2 (register chain) ----
    if (tau >= 1 && tau <= LL) {
      float y = 0.f;
      #pragma unroll
      for (int q = 0; q < 16; ++q) {
        float4 h4 = h1p[q];
        y += w2[4*q+0]*h4.x + w2[4*q+1]*h4.y + w2[4*q+2]*h4.z + w2[4*q+3]*h4.w;
      }
      y = wave_red8(y);
      xin2 = y + bias2;
    }
  }
}

// ------------------------------------------- attention row @ eos + decode head
// O2 is stored ENCODED (h+2). Decode: q explicitly; scores via qsum trick;
// att_z via sum(p)=1 -> subtract 2 at the end.
__global__ __launch_bounds__(256) void k_attn(
    const float* __restrict__ O2, const int* __restrict__ eos,
    const float* __restrict__ Wc, const float* __restrict__ bc,
    const float* __restrict__ Wd, const float* __restrict__ bd,
    float* __restrict__ out)
{
  const int b = blockIdx.x;
  const int tid = threadIdx.x;
  const int te = eos[b];
  __shared__ __align__(16) float q[DD];
  __shared__ float ps[LL];
  __shared__ float red[256];
  __shared__ __align__(16) float din[2 * DD];
  __shared__ __align__(16) float dvec[DD];
  const float* Ob = O2 + (long)b * LL * DD;
  const float4* Ob4 = (const float4*)Ob;

  float qpart = 0.f;
  for (int i = tid; i < DD; i += 256) {
    float v = Ob[(long)te * DD + i] - 2.0f;   // decode
    q[i] = v; qpart += v;
  }
  red[tid] = qpart; __syncthreads();
  for (int off = 128; off > 0; off >>= 1) {
    if (tid < off) red[tid] += red[tid + off];
    __syncthreads();
  }
  const float qsum = red[0];
  __syncthreads();
  const float4* q4 = (const float4*)q;

  // masked scores: raw dot(o_enc, q) - 2*qsum == dot(o, q)
  for (int ss = tid; ss < LL; ss += 256) {
    float sc = -1.0e9f;
    if (ss < te) {
      float4 acc = {0.f, 0.f, 0.f, 0.f};
      for (int kq = 0; kq < 128; ++kq) {
        float4 o = Ob4[ss * 128 + kq];
        float4 qq = q4[kq];
        acc.x += o.x*qq.x; acc.y += o.y*qq.y; acc.z += o.z*qq.z; acc.w += o.w*qq.w;
      }
      sc = acc.x + acc.y + acc.z + acc.w - 2.0f * qsum;
    }
    ps[ss] = sc;
  }
  __syncthreads();
  float m = -3.0e38f;
  for (int ss = tid; ss < LL; ss += 256) m = fmaxf(m, ps[ss]);
  red[tid] = m; __syncthreads();
  for (int off = 128; off > 0; off >>= 1) {
    if (tid < off) red[tid] = fmaxf(red[tid], red[tid + off]);
    __syncthreads();
  }
  m = red[0]; __syncthreads();
  float lsum = 0.f;
  for (int ss = tid; ss < LL; ss += 256) {
    float e = expf(ps[ss] - m);
    ps[ss] = e; lsum += e;
  }
  __syncthreads();
  red[tid] = lsum; __syncthreads();
  for (int off = 128; off > 0; off >>= 1) {
    if (tid < off) red[tid] += red[tid + off];
    __syncthreads();
  }
  const float inv = 1.0f / red[0];
  __syncthreads();
  for (int ss = tid; ss < LL; ss += 256) ps[ss] *= inv;
  __syncthreads();

  // att_z (encoded: sum p*o_enc - 2 since sum p = 1), z-copy (already decoded)
  if (tid < 128) {
    float4 acc = {0.f, 0.f, 0.f, 0.f};
    for (int ss = 0; ss < LL; ++ss) {
      float p = ps[ss];
      if (p != 0.0f) {
        float4 o = Ob4[ss * 128 + tid];
        acc.x += p*o.x; acc.y += p*o.y; acc.z += p*o.z; acc.w += p*o.w;
      }
    }
    acc.x -= 2.0f; acc.y -= 2.0f; acc.z -= 2.0f; acc.w -= 2.0f;
    ((float4*)din)[tid] = acc;
  } else {
    const int c = tid - 128;
    ((float4*)din)[128 + c] = q4[c];
  }
  __syncthreads();

  const float4* din4 = (const float4*)din;
  for (int jj = tid; jj < DD; jj += 256) {
    const float4* wrow = (const float4*)(Wc + (long)jj * 2 * DD);
    float4 acc = {0.f, 0.f, 0.f, 0.f};
    for (int iq = 0; iq < 256; ++iq) {
      float4 w = wrow[iq]; float4 d = din4[iq];
      acc.x += w.x*d.x; acc.y += w.y*d.y; acc.z += w.z*d.z; acc.w += w.w*d.w;
    }
    dvec[jj] = bc[jj] + acc.x + acc.y + acc.z + acc.w;
  }
  __syncthreads();

  if (tid < NCLS) {
    const float4* wrow = (const float4*)(Wd + (long)tid * DD);
    const float4* dv4 = (const float4*)dvec;
    float4 acc = {0.f, 0.f, 0.f, 0.f};
    for (int iq = 0; iq < 128; ++iq) {
      float4 w = wrow[iq]; float4 d = dv4[iq];
      acc.x += w.x*d.x; acc.y += w.y*d.y; acc.z += w.z*d.z; acc.w += w.w*d.w;
    }
    out[b * NCLS + tid] = bd[tid] + acc.x + acc.y + acc.z + acc.w;
  }
}

extern "C" void kernel_launch(void* const* d_in, const int* in_sizes, int n_in,
                              void* d_out, int out_size, void* d_ws, size_t ws_size,
                              hipStream_t stream)
{
  const int*   x    = (const int*)  d_in[0];
  const int*   eos  = (const int*)  d_in[1];
  const float* emb  = (const float*)d_in[2];
  const float* W_ih = (const float*)d_in[3];
  const float* W_hh = (const float*)d_in[4];
  const float* b_ih = (const float*)d_in[5];
  const float* b_hh = (const float*)d_in[6];
  const float* Wc   = (const float*)d_in[7];
  const float* bc   = (const float*)d_in[8];
  const float* Wd   = (const float*)d_in[9];
  const float* bd   = (const float*)d_in[10];
  float* out = (float*)d_out;

  // workspace: Abuf (h2+2) | Bbuf (xproj->h1+2). Poison 0xAA = -3e-13 < 1 => "not ready".
  float* Abuf = (float*)d_ws;
  float* Bbuf = Abuf + (size_t)NB * LL * DD;

  k_gemm_embed<<<2048, 256, 0, stream>>>(x, emb, W_ih, b_ih, b_hh, Bbuf);
  k_scan<<<256, 256, 0, stream>>>(W_ih, W_hh, b_ih, b_hh, Bbuf, Abuf);
  k_attn<<<NB, 256, 0, stream>>>(Abuf, eos, Wc, bc, Wd, bd, out);
}

// Round 3
// 2883.900 us; speedup vs baseline: 2.5151x; 1.1116x over previous
//
#include <hip/hip_runtime.h>
#include <cmath>

#define NB   16
#define LL   1024
#define DD   512
#define NCLS 64

// ---------------------------------------------- fused embed-gather + proj GEMM
// C[m][n] = b1[n] + b2[n] + sum_k emb[x[m]][k] * W[n][k]   (M=16384, N=K=512)
__global__ __launch_bounds__(256) void k_gemm_embed(
    const int* __restrict__ x, const float* __restrict__ emb,
    const float* __restrict__ W, const float* __restrict__ b1,
    const float* __restrict__ b2, float* __restrict__ C)
{
  __shared__ __align__(16) float As[32][68];  // [k][m], +4 pad
  __shared__ __align__(16) float Ws[32][68];  // [k][n]
  const int tid = threadIdx.x;
  const int n0 = (blockIdx.x & 7) * 64;
  const int m0 = (blockIdx.x >> 3) * 64;
  const int tm = tid & 15, tn = tid >> 4;
  float acc[4][4] = {};

  const int f0 = tid * 2, f1 = tid * 2 + 1;
  const int r0 = f0 >> 3, q0 = f0 & 7;
  const int r1 = f1 >> 3, q1 = f1 & 7;
  const long arow0 = (long)x[m0 + r0] * DD;
  const long arow1 = (long)x[m0 + r1] * DD;
  const long wrow0 = (long)(n0 + r0) * DD;
  const long wrow1 = (long)(n0 + r1) * DD;

  for (int k0 = 0; k0 < DD; k0 += 32) {
    float4 va = *(const float4*)(emb + arow0 + k0 + q0 * 4);
    float4 vb = *(const float4*)(emb + arow1 + k0 + q1 * 4);
    float4 wa = *(const float4*)(W + wrow0 + k0 + q0 * 4);
    float4 wb = *(const float4*)(W + wrow1 + k0 + q1 * 4);
    __syncthreads();
    As[q0*4+0][r0]=va.x; As[q0*4+1][r0]=va.y; As[q0*4+2][r0]=va.z; As[q0*4+3][r0]=va.w;
    As[q1*4+0][r1]=vb.x; As[q1*4+1][r1]=vb.y; As[q1*4+2][r1]=vb.z; As[q1*4+3][r1]=vb.w;
    Ws[q0*4+0][r0]=wa.x; Ws[q0*4+1][r0]=wa.y; Ws[q0*4+2][r0]=wa.z; Ws[q0*4+3][r0]=wa.w;
    Ws[q1*4+0][r1]=wb.x; Ws[q1*4+1][r1]=wb.y; Ws[q1*4+2][r1]=wb.z; Ws[q1*4+3][r1]=wb.w;
    __syncthreads();
    #pragma unroll
    for (int kk = 0; kk < 32; ++kk) {
      float4 a = *(const float4*)&As[kk][tm * 4];
      float4 w = *(const float4*)&Ws[kk][tn * 4];
      acc[0][0]+=a.x*w.x; acc[0][1]+=a.x*w.y; acc[0][2]+=a.x*w.z; acc[0][3]+=a.x*w.w;
      acc[1][0]+=a.y*w.x; acc[1][1]+=a.y*w.y; acc[1][2]+=a.y*w.z; acc[1][3]+=a.y*w.w;
      acc[2][0]+=a.z*w.x; acc[2][1]+=a.z*w.y; acc[2][2]+=a.z*w.z; acc[2][3]+=a.z*w.w;
      acc[3][0]+=a.w*w.x; acc[3][1]+=a.w*w.y; acc[3][2]+=a.w*w.z; acc[3][3]+=a.w*w.w;
    }
  }
  float bj[4];
  #pragma unroll
  for (int j = 0; j < 4; ++j)
    bj[j] = b1[n0 + tn * 4 + j] + b2[n0 + tn * 4 + j];
  #pragma unroll
  for (int i = 0; i < 4; ++i) {
    const int m = m0 + tm * 4 + i;
    float4 o = { acc[i][0]+bj[0], acc[i][1]+bj[1], acc[i][2]+bj[2], acc[i][3]+bj[3] };
    *(float4*)(C + (long)m * DD + n0 + tn * 4) = o;
  }
}

// ---------------------------------------------------------------- scan helpers
__device__ __forceinline__ float wave_red8(float y) {
  // sum over 8-lane groups (lanes l^1, l^2, l^4) — stays within 32-lane halves
  y += __int_as_float(__builtin_amdgcn_ds_swizzle(__float_as_int(y), 0x041F));
  y += __int_as_float(__builtin_amdgcn_ds_swizzle(__float_as_int(y), 0x081F));
  y += __int_as_float(__builtin_amdgcn_ds_swizzle(__float_as_int(y), 0x101F));
  return y;
}

__device__ __forceinline__ float poll_ld(const float* p) {
  return __hip_atomic_load(p, __ATOMIC_RELAXED, __HIP_MEMORY_SCOPE_AGENT);
}
__device__ __forceinline__ void enc_st(float* p, float v) {
  __hip_atomic_store(p, v + 2.0f, __ATOMIC_RELAXED, __HIP_MEMORY_SCOPE_AGENT);
}

// ------------------------------------------------- persistent 2-layer RNN scan
// 256 WGs = 16 batches x 16 WGs. Each WG owns 32 rows of ALL THREE matrices
// (Whh1, Wih2, Whh2): 192 weight floats/thread, PINNED in VGPRs via empty
// inline-asm "+v" (r2 showed VGPR_Count=116 -> compiler was re-fetching
// weights from L2 every step; the asm is an opaque def that forbids remat).
// Handshake = data-poll on h+2 encoding: one coherence hop per step.
__global__ __launch_bounds__(256, 1) void k_scan(
    const float* __restrict__ W_ih, const float* __restrict__ W_hh,
    const float* __restrict__ b_ih, const float* __restrict__ b_hh,
    float* __restrict__ Bbuf,   // in: xproj layer1 -> h1+2 (in-place)
    float* __restrict__ Abuf)   // h2+2 (O2, encoded)
{
  const int g = blockIdx.x;
  const int b = g & 15;            // batch (g%8 == b%8 -> one XCD per batch-pair)
  const int j = g >> 4;            // WG index within batch [0,16)
  const int tid = threadIdx.x;
  const int rl  = tid >> 3;        // row_local [0,32)
  const int part = tid & 7;        // k-part [0,8), 64 elems each
  const int row = j * 32 + rl;     // global hidden row
  const bool leader = (part == 0);

  __shared__ __align__(16) float hS1[2][8 * 68];  // staged h1(tau-1), dbl-buffered
  __shared__ __align__(16) float hS2[2][8 * 68];  // staged h2(tau-3)

  float w1[64], w2[64], w3[64];
  {
    const float* p1 = W_hh + (long)row * DD + part * 64;                 // Whh l0
    const float* p2 = W_ih + (long)DD * DD + (long)row * DD + part * 64; // Wih l1
    const float* p3 = W_hh + (long)DD * DD + (long)row * DD + part * 64; // Whh l1
    #pragma unroll
    for (int q = 0; q < 64; ++q) { w1[q] = p1[q]; w2[q] = p2[q]; w3[q] = p3[q]; }
  }
  // pin all 192 weights in VGPRs: opaque def, no sinking / remat allowed
  #pragma unroll
  for (int q = 0; q < 64; ++q) {
    asm volatile("" : "+v"(w1[q]));
    asm volatile("" : "+v"(w2[q]));
    asm volatile("" : "+v"(w3[q]));
  }
  const float bias2 = b_ih[DD + row] + b_hh[DD + row];
  float xin2 = 0.f;   // holds xin2(tau-2)+bias2 entering step tau

  float* Bb = Bbuf + (long)b * LL * DD;
  float* Ab = Abuf + (long)b * LL * DD;

  const int i0 = tid, i1 = tid + 256;
  const int d0 = (i0 >> 6) * 68 + (i0 & 63);
  const int d1 = (i1 >> 6) * 68 + (i1 & 63);

  for (int tau = 0; tau <= LL + 1; ++tau) {
    const int bufi = tau & 1;
    const bool st1 = (tau >= 1 && tau <= LL);
    const bool st2 = (tau >= 3);
    float xpv = 0.f;
    if (leader && tau < LL) xpv = Bb[(long)tau * DD + row];  // prefetch xproj early

    // ---- combined stage h1(tau-1) + h2(tau-3): one spin, 4 loads in flight ----
    if (st1 | st2) {
      const float* s1 = Bb + (long)(tau - 1) * DD;
      const float* s2 = Ab + (long)(tau - 3) * DD;
      float v0 = 3.f, v1 = 3.f, u0 = 3.f, u1 = 3.f;
      if (st1) { v0 = poll_ld(s1 + i0); v1 = poll_ld(s1 + i1); }
      if (st2) { u0 = poll_ld(s2 + i0); u1 = poll_ld(s2 + i1); }
      while (fminf(fminf(v0, v1), fminf(u0, u1)) <= 1.0f) {
        if (st1) { v0 = poll_ld(s1 + i0); v1 = poll_ld(s1 + i1); }
        if (st2) { u0 = poll_ld(s2 + i0); u1 = poll_ld(s2 + i1); }
      }
      if (st1) { hS1[bufi][d0] = v0 - 2.0f; hS1[bufi][d1] = v1 - 2.0f; }
      if (st2) { hS2[bufi][d0] = u0 - 2.0f; hS2[bufi][d1] = u1 - 2.0f; }
    }
    __syncthreads();   // single barrier/step (dbl-buffered LDS)

    const float4* h1p = (const float4*)&hS1[bufi][part * 68];
    const float4* h2p = (const float4*)&hS2[bufi][part * 68];

    // ---- M1: h1(tau) = tanh(xproj + Whh1 . h1(tau-1)) — the critical chain ----
    if (tau < LL) {
      float y = 0.f;
      if (tau >= 1) {
        #pragma unroll
        for (int q = 0; q < 16; ++q) {
          float4 h4 = h1p[q];
          y += w1[4*q+0]*h4.x + w1[4*q+1]*h4.y + w1[4*q+2]*h4.z + w1[4*q+3]*h4.w;
        }
      }
      y = wave_red8(y);
      if (leader) enc_st(Bb + (long)tau * DD + row, tanhf(xpv + y));
    }
    // ---- M3: h2(tau-2) = tanh(xin2(tau-2) + Whh2 . h2(tau-3)) ----
    if (tau >= 2) {
      float y = 0.f;
      if (tau >= 3) {
        #pragma unroll
        for (int q = 0; q < 16; ++q) {
          float4 h4 = h2p[q];
          y += w3[4*q+0]*h4.x + w3[4*q+1]*h4.y + w3[4*q+2]*h4.z + w3[4*q+3]*h4.w;
        }
      }
      y = wave_red8(y);
      if (leader) enc_st(Ab + (long)(tau - 2) * DD + row, tanhf(xin2 + y));
    }
    // ---- M2: xin2(tau-1) = Wih2 . h1(tau-1) + bias2 (register chain) ----
    if (st1) {
      float y = 0.f;
      #pragma unroll
      for (int q = 0; q < 16; ++q) {
        float4 h4 = h1p[q];
        y += w2[4*q+0]*h4.x + w2[4*q+1]*h4.y + w2[4*q+2]*h4.z + w2[4*q+3]*h4.w;
      }
      y = wave_red8(y);
      xin2 = y + bias2;
    }
  }
}

// ------------------------------------------- attention row @ eos + decode head
// O2 is stored ENCODED (h+2). Decode: q explicitly; scores via qsum trick;
// att_z via sum(p)=1 -> subtract 2 at the end.
__global__ __launch_bounds__(256) void k_attn(
    const float* __restrict__ O2, const int* __restrict__ eos,
    const float* __restrict__ Wc, const float* __restrict__ bc,
    const float* __restrict__ Wd, const float* __restrict__ bd,
    float* __restrict__ out)
{
  const int b = blockIdx.x;
  const int tid = threadIdx.x;
  const int te = eos[b];
  __shared__ __align__(16) float q[DD];
  __shared__ float ps[LL];
  __shared__ float red[256];
  __shared__ __align__(16) float din[2 * DD];
  __shared__ __align__(16) float dvec[DD];
  const float* Ob = O2 + (long)b * LL * DD;
  const float4* Ob4 = (const float4*)Ob;

  float qpart = 0.f;
  for (int i = tid; i < DD; i += 256) {
    float v = Ob[(long)te * DD + i] - 2.0f;   // decode
    q[i] = v; qpart += v;
  }
  red[tid] = qpart; __syncthreads();
  for (int off = 128; off > 0; off >>= 1) {
    if (tid < off) red[tid] += red[tid + off];
    __syncthreads();
  }
  const float qsum = red[0];
  __syncthreads();
  const float4* q4 = (const float4*)q;

  // masked scores: raw dot(o_enc, q) - 2*qsum == dot(o, q)
  for (int ss = tid; ss < LL; ss += 256) {
    float sc = -1.0e9f;
    if (ss < te) {
      float4 acc = {0.f, 0.f, 0.f, 0.f};
      for (int kq = 0; kq < 128; ++kq) {
        float4 o = Ob4[ss * 128 + kq];
        float4 qq = q4[kq];
        acc.x += o.x*qq.x; acc.y += o.y*qq.y; acc.z += o.z*qq.z; acc.w += o.w*qq.w;
      }
      sc = acc.x + acc.y + acc.z + acc.w - 2.0f * qsum;
    }
    ps[ss] = sc;
  }
  __syncthreads();
  float m = -3.0e38f;
  for (int ss = tid; ss < LL; ss += 256) m = fmaxf(m, ps[ss]);
  red[tid] = m; __syncthreads();
  for (int off = 128; off > 0; off >>= 1) {
    if (tid < off) red[tid] = fmaxf(red[tid], red[tid + off]);
    __syncthreads();
  }
  m = red[0]; __syncthreads();
  float lsum = 0.f;
  for (int ss = tid; ss < LL; ss += 256) {
    float e = expf(ps[ss] - m);
    ps[ss] = e; lsum += e;
  }
  __syncthreads();
  red[tid] = lsum; __syncthreads();
  for (int off = 128; off > 0; off >>= 1) {
    if (tid < off) red[tid] += red[tid + off];
    __syncthreads();
  }
  const float inv = 1.0f / red[0];
  __syncthreads();
  for (int ss = tid; ss < LL; ss += 256) ps[ss] *= inv;
  __syncthreads();

  // att_z (encoded: sum p*o_enc - 2 since sum p = 1), z-copy (already decoded)
  if (tid < 128) {
    float4 acc = {0.f, 0.f, 0.f, 0.f};
    for (int ss = 0; ss < LL; ++ss) {
      float p = ps[ss];
      if (p != 0.0f) {
        float4 o = Ob4[ss * 128 + tid];
        acc.x += p*o.x; acc.y += p*o.y; acc.z += p*o.z; acc.w += p*o.w;
      }
    }
    acc.x -= 2.0f; acc.y -= 2.0f; acc.z -= 2.0f; acc.w -= 2.0f;
    ((float4*)din)[tid] = acc;
  } else {
    const int c = tid - 128;
    ((float4*)din)[128 + c] = q4[c];
  }
  __syncthreads();

  const float4* din4 = (const float4*)din;
  for (int jj = tid; jj < DD; jj += 256) {
    const float4* wrow = (const float4*)(Wc + (long)jj * 2 * DD);
    float4 acc = {0.f, 0.f, 0.f, 0.f};
    for (int iq = 0; iq < 256; ++iq) {
      float4 w = wrow[iq]; float4 d = din4[iq];
      acc.x += w.x*d.x; acc.y += w.y*d.y; acc.z += w.z*d.z; acc.w += w.w*d.w;
    }
    dvec[jj] = bc[jj] + acc.x + acc.y + acc.z + acc.w;
  }
  __syncthreads();

  if (tid < NCLS) {
    const float4* wrow = (const float4*)(Wd + (long)tid * DD);
    const float4* dv4 = (const float4*)dvec;
    float4 acc = {0.f, 0.f, 0.f, 0.f};
    for (int iq = 0; iq < 128; ++iq) {
      float4 w = wrow[iq]; float4 d = dv4[iq];
      acc.x += w.x*d.x; acc.y += w.y*d.y; acc.z += w.z*d.z; acc.w += w.w*d.w;
    }
    out[b * NCLS + tid] = bd[tid] + acc.x + acc.y + acc.z + acc.w;
  }
}

extern "C" void kernel_launch(void* const* d_in, const int* in_sizes, int n_in,
                              void* d_out, int out_size, void* d_ws, size_t ws_size,
                              hipStream_t stream)
{
  const int*   x    = (const int*)  d_in[0];
  const int*   eos  = (const int*)  d_in[1];
  const float* emb  = (const float*)d_in[2];
  const float* W_ih = (const float*)d_in[3];
  const float* W_hh = (const float*)d_in[4];
  const float* b_ih = (const float*)d_in[5];
  const float* b_hh = (const float*)d_in[6];
  const float* Wc   = (const float*)d_in[7];
  const float* bc   = (const float*)d_in[8];
  const float* Wd   = (const float*)d_in[9];
  const float* bd   = (const float*)d_in[10];
  float* out = (float*)d_out;

  // workspace: Abuf (h2+2) | Bbuf (xproj->h1+2). Poison 0xAA = -3e-13 < 1 => "not ready".
  float* Abuf = (float*)d_ws;
  float* Bbuf = Abuf + (size_t)NB * LL * DD;

  k_gemm_embed<<<2048, 256, 0, stream>>>(x, emb, W_ih, b_ih, b_hh, Bbuf);
  k_scan<<<256, 256, 0, stream>>>(W_ih, W_hh, b_ih, b_hh, Bbuf, Abuf);
  k_attn<<<NB, 256, 0, stream>>>(Abuf, eos, Wc, bc, Wd, bd, out);
}